// Round 8
// baseline (6102.135 us; speedup 1.0000x reference)
//
#include <hip/hip_runtime.h>

// Chamfer distance, B=4, N=8192, fp32 3-D points, MI355X.
// Round 8: r7 structure (inline-asm MFMA -> VGPR accs, verified) with the
// two suspected hidden costs removed:
//  - __launch_bounds__(512,2): 256-reg budget for ~160 live -> no scratch
//    spills (r6/r7 caps of 128/170 were at/below the live set)
//  - raw s_barrier (no vmcnt drain) every 16 tiles: 8 waves/block stay
//    L1-coherent on the shared B stream without killing the prefetch
//  - 6-tile register prefetch pipeline (~3 iters ~ 400cyc lead > L2 225cyc),
//    fully unrolled loop -> all B offsets are compile-time immediates

typedef _Float16 half8  __attribute__((ext_vector_type(8)));
typedef float    f32x16 __attribute__((ext_vector_type(16)));

#define NPTS   8192
#define NB     4
#define TILES  256                 // 32-point tiles per (cloud,batch)
#define SPLITS 4                   // B-range splits per direction
#define TPW    (TILES / SPLITS)    // 64 B-tiles per sweep

#define MFMA_V(d, a, b, c)                                             \
    asm("v_mfma_f32_32x32x16_f16 %0, %1, %2, %3"                       \
        : "=&v"(d) : "v"(a), "v"(b), "v"(c))

// ---------- prep: BOTH clouds into B-role fragments ----------
// wsB layout: [cloud][b][tile][lane], cloud0=pc1, cloud1=pc2.
__global__ __launch_bounds__(256) void chamfer_prep(
    const float* __restrict__ pc1, const float* __restrict__ pc2,
    half8* __restrict__ wsB)
{
    const int tid   = blockIdx.x * 256 + threadIdx.x;  // 0..131071
    const int lane  = tid & 63;
    const int tile  = (tid >> 6) & (TILES - 1);
    const int b     = (tid >> 14) & (NB - 1);
    const int cloud = tid >> 16;

    const float* pc = cloud ? pc2 : pc1;
    const int col = lane & 31, g = lane >> 5;

    const float* Q = pc + ((size_t)b * NPTS + tile * 32 + col) * 3;
    const float qx = Q[0], qy = Q[1], qz = Q[2];

    const _Float16 hx = (_Float16)qx, hy = (_Float16)qy, hz = (_Float16)qz;
    const _Float16 lx = (_Float16)(qx - (float)hx);
    const _Float16 ly = (_Float16)(qy - (float)hy);
    const _Float16 lz = (_Float16)(qz - (float)hz);
    const float sq = fmaf(qx, qx, fmaf(qy, qy, qz * qz));
    const _Float16 sh = (_Float16)sq;
    const _Float16 sl = (_Float16)(sq - (float)sh);

    const _Float16 nhx = (_Float16)(-2.0f * (float)hx);
    const _Float16 nhy = (_Float16)(-2.0f * (float)hy);
    const _Float16 nhz = (_Float16)(-2.0f * (float)hz);
    const _Float16 nlx = (_Float16)(-2.0f * (float)lx);
    const _Float16 nly = (_Float16)(-2.0f * (float)ly);
    const _Float16 nlz = (_Float16)(-2.0f * (float)lz);
    const _Float16 one = (_Float16)1.0f, zz = (_Float16)0.0f;

    half8 v;
    if (g == 0) v = (half8){nhx, nhy, nhz, nlx, nly, nlz, nhx, nhy};
    else        v = (half8){nhz, one, one, sh,  sl,  zz,  zz,  zz};
    wsB[tid] = v;
}

// ---------- main: 512 blocks x 512 thr (8 waves) ----------
// block = (dir, b, qsplit, ptile-of-512); wave = 64 p-rows (2 A-tiles).
__global__ __launch_bounds__(512, 2) void chamfer_main(
    const float* __restrict__ pc1, const float* __restrict__ pc2,
    const half8* __restrict__ wsB, float* __restrict__ ws_row)
{
    int bid = blockIdx.x;
    const int pt  = bid & 15;            bid >>= 4;
    const int qs  = bid & (SPLITS - 1);  bid >>= 2;
    const int b   = bid & (NB - 1);      bid >>= 2;
    const int dir = bid;

    const int tid = threadIdx.x;
    const int w = tid >> 6, lane = tid & 63;
    const int col = lane & 31, g = lane >> 5;
    const int pbase = pt * 512 + w * 64;       // this wave: rows pbase..pbase+63

    const float* Acl = dir ? pc2 : pc1;        // row side
    const int    bcl = dir ? 0 : 1;            // col side (B-role cloud)

    const _Float16 one = (_Float16)1.0f, zz = (_Float16)0.0f;

    // Two A fragments (rows pbase+col and pbase+32+col).
    half8 a0, a1;
    #pragma unroll
    for (int h = 0; h < 2; ++h) {
        const float* P = Acl + ((size_t)b * NPTS + pbase + h * 32 + col) * 3;
        const float px = P[0], py = P[1], pz = P[2];
        const _Float16 hx = (_Float16)px, hy = (_Float16)py, hz = (_Float16)pz;
        const _Float16 lx = (_Float16)(px - (float)hx);
        const _Float16 ly = (_Float16)(py - (float)hy);
        const _Float16 lz = (_Float16)(pz - (float)hz);
        const float sq1 = fmaf(px, px, fmaf(py, py, pz * pz));
        const _Float16 sh = (_Float16)sq1;
        const _Float16 sl = (_Float16)(sq1 - (float)sh);
        half8 a;
        if (g == 0) a = (half8){hx, hy, hz, hx, hy, hz, lx, ly};
        else        a = (half8){lz, sh, sl, one, one, zz, zz, zz};
        if (h == 0) a0 = a; else a1 = a;
    }

    const half8* Bw = wsB + (((size_t)bcl * NB + b) * TILES + qs * TPW) * 64 + lane;

    f32x16 rowmin0, rowmin1;
    #pragma unroll
    for (int r = 0; r < 16; ++r) { rowmin0[r] = 3.402823466e+38f;
                                   rowmin1[r] = 3.402823466e+38f; }
    f32x16 zero16;
    #pragma unroll
    for (int r = 0; r < 16; ++r) zero16[r] = 0.0f;

    // 6-tile prefetch pipeline (3 iterations deep).
    half8 p0 = Bw[0 * 64], p1 = Bw[1 * 64];
    half8 p2 = Bw[2 * 64], p3 = Bw[3 * 64];
    half8 p4 = Bw[4 * 64], p5 = Bw[5 * 64];

    #pragma unroll
    for (int t = 0; t < TPW; t += 2) {
        if (t && !(t & 15))
            __builtin_amdgcn_s_barrier();   // raw barrier: align waves for L1
                                            // reuse, NO vmcnt drain

        // prefetch t+6, t+7 (compile-time offsets; tail overruns <=6KB into
        // ws_row, loaded but never consumed)
        const half8 m0 = Bw[(t + 6) * 64];
        const half8 m1 = Bw[(t + 7) * 64];

        f32x16 acc00, acc01, acc10, acc11;
        MFMA_V(acc00, a0, p0, zero16);
        MFMA_V(acc01, a0, p1, zero16);
        MFMA_V(acc10, a1, p0, zero16);
        MFMA_V(acc11, a1, p1, zero16);

        // hazard gap: no VALU read of accs until >=16 cyc after last issue
        __builtin_amdgcn_sched_barrier(0);
        asm volatile("s_nop 7\n\ts_nop 7");
        __builtin_amdgcn_sched_barrier(0);

        #pragma unroll
        for (int r = 0; r < 16; ++r)
            rowmin0[r] = fminf(fminf(acc00[r], acc01[r]), rowmin0[r]);
        #pragma unroll
        for (int r = 0; r < 16; ++r)
            rowmin1[r] = fminf(fminf(acc10[r], acc11[r]), rowmin1[r]);

        p0 = p2; p1 = p3; p2 = p4; p3 = p5; p4 = m0; p5 = m1;
    }

    // Cross-column min (32 cols) + store. row map: (r&3)+8*(r>>2)+4*g (m74/m101).
    const size_t obase = (((size_t)dir * NB + b) * SPLITS + qs) * NPTS + pbase;
    #pragma unroll
    for (int r = 0; r < 16; ++r) {
        float v = rowmin0[r];
        v = fminf(v, __shfl_xor(v, 1, 64));
        v = fminf(v, __shfl_xor(v, 2, 64));
        v = fminf(v, __shfl_xor(v, 4, 64));
        v = fminf(v, __shfl_xor(v, 8, 64));
        v = fminf(v, __shfl_xor(v, 16, 64));
        float u = rowmin1[r];
        u = fminf(u, __shfl_xor(u, 1, 64));
        u = fminf(u, __shfl_xor(u, 2, 64));
        u = fminf(u, __shfl_xor(u, 4, 64));
        u = fminf(u, __shfl_xor(u, 8, 64));
        u = fminf(u, __shfl_xor(u, 16, 64));
        if (col == 0) {
            const int row = (r & 3) + 8 * (r >> 2) + 4 * g;
            ws_row[obase + row]      = v;
            ws_row[obase + 32 + row] = u;
        }
    }
}

// ---------- reduce: 64 blocks; min over 4 splits, block partial sums ----------
__global__ __launch_bounds__(256) void chamfer_reduce(
    const float* __restrict__ ws_row, float* __restrict__ partial)
{
    int bid = blockIdx.x;                    // 2 dir x 4 b x 8 slices
    const int sl  = bid & 7; bid >>= 3;
    const int b   = bid & 3; bid >>= 2;
    const int dir = bid;

    const float* base = ws_row + (((size_t)dir * NB + b) * SPLITS) * NPTS;
    float sum = 0.0f;
    for (int i = threadIdx.x; i < 1024; i += 256) {
        const int p = sl * 1024 + i;
        sum += fminf(fminf(base[p],            base[NPTS + p]),
                     fminf(base[2 * NPTS + p], base[3 * NPTS + p]));
    }

    for (int off = 32; off; off >>= 1) sum += __shfl_down(sum, off, 64);
    __shared__ float red[4];
    if (!(threadIdx.x & 63)) red[threadIdx.x >> 6] = sum;
    __syncthreads();
    if (!threadIdx.x)
        partial[((dir * NB + b) << 3) + sl] = red[0] + red[1] + red[2] + red[3];
}

// ---------- final: 4 blocks x 64 thr ----------
__global__ __launch_bounds__(64) void chamfer_final(
    const float* __restrict__ partial, float* __restrict__ out)
{
    const int b = blockIdx.x, t = threadIdx.x;
    float v = 0.0f;
    if (t < 16) {
        const int dir = t >> 3, sl = t & 7;
        v = partial[((dir * NB + b) << 3) + sl];
    }
    for (int off = 32; off; off >>= 1) v += __shfl_down(v, off, 64);
    if (!t) out[b] = v * (1.0f / (float)NPTS);
}

extern "C" void kernel_launch(void* const* d_in, const int* in_sizes, int n_in,
                              void* d_out, int out_size, void* d_ws, size_t ws_size,
                              hipStream_t stream)
{
    const float* pc1 = (const float*)d_in[0];
    const float* pc2 = (const float*)d_in[1];
    float* out = (float*)d_out;

    char* ws = (char*)d_ws;
    half8* wsB     = (half8*)ws;                         // 2 MiB (+<=6KB tail overrun pads into ws_row)
    float* ws_row  = (float*)(ws + (2 << 20));           // 1 MiB
    float* partial = (float*)(ws + (3 << 20));           // 256 B

    chamfer_prep<<<512, 256, 0, stream>>>(pc1, pc2, wsB);
    chamfer_main<<<512, 512, 0, stream>>>(pc1, pc2, wsB, ws_row);
    chamfer_reduce<<<64, 256, 0, stream>>>(ws_row, partial);
    chamfer_final<<<NB, 64, 0, stream>>>(partial, out);
}

// Round 9
// 33.638 us; speedup vs baseline: 181.4070x; 181.4070x over previous
//
#include <hip/hip_runtime.h>

// Chamfer distance, B=4, N=8192, fp32 3-D points, MI355X.
// Round 9: LDS-resident B-fragments, 3 kernels, barrier-free inner loop.
//  - each block BUILDS its own 64-tile fragment window in LDS (no prep
//    kernel, no global wsB, no L1/L2 barrier-window games)
//  - inner loop: ds_read_b128 at compile-time offsets; after the build
//    __syncthreads the LDS is read-only -> NO barriers in the loop
//  - 4-tile register ring (2-iteration lead > ~120cyc LDS latency),
//    #pragma unroll 4 + per-iter sched_barrier walls bound reg pressure
//    (r8 lesson: full unroll + free-floating loads = spill disaster)
//  - inline-asm MFMA -> accs in arch VGPRs (r7 lesson: intrinsic accs land
//    in AGPRs; VALU can't read AGPRs -> 16 v_accvgpr_read per acc per fold)
// K-slot packing (verified r3-r8):
//   A g0={hx,hy,hz,hx,hy,hz,lx,ly}  g1={lz,sh,sl,1,1,0,0,0}
//   B g0={-2hx,-2hy,-2hz,-2lx,-2ly,-2lz,-2hx,-2hy}  g1={-2hz,1,1,sh,sl,0,0,0}
//   => acc = sq1 + sq2 - 2(h.h' + h.l' + l.h')   (l.l' term ~2e-5 dropped)

typedef _Float16 half8  __attribute__((ext_vector_type(8)));
typedef float    f32x16 __attribute__((ext_vector_type(16)));

#define NPTS   8192
#define NB     4
#define SPLITS 4
#define TPW    64                  // B-tiles per window (= per wave sweep)
#define QWIN   (TPW * 32)          // 2048 q-points per window

#define MFMA_V(d, a, b, c)                                             \
    asm("v_mfma_f32_32x32x16_f16 %0, %1, %2, %3"                       \
        : "=&v"(d) : "v"(a), "v"(b), "v"(c))

// ---------- main: 1024 blocks x 256 thr (4 waves) ----------
// block = (dir, b, qsplit, ptile-of-256); wave = 64 p-rows (2 A-tiles).
__global__ __launch_bounds__(256, 3) void chamfer_main(
    const float* __restrict__ pc1, const float* __restrict__ pc2,
    float* __restrict__ ws_row)
{
    // [tile][lane] fragments; +4 pad tiles so the prefetch ring's tail
    // reads (never consumed) stay in-bounds.
    __shared__ half8 Bf[(TPW + 4) * 64];

    int bid = blockIdx.x;
    const int pt  = bid & 31;            bid >>= 5;
    const int qs  = bid & (SPLITS - 1);  bid >>= 2;
    const int b   = bid & (NB - 1);      bid >>= 2;
    const int dir = bid;

    const int tid = threadIdx.x;
    const int w = tid >> 6, lane = tid & 63;
    const int col = lane & 31, g = lane >> 5;
    const int pbase = pt * 256 + w * 64;       // this wave: rows pbase..pbase+63

    const float* Acl = dir ? pc2 : pc1;        // row side
    const float* Bcl = dir ? pc1 : pc2;        // col side

    const _Float16 one = (_Float16)1.0f, zz = (_Float16)0.0f;

    // ---- build this block's B-fragment window in LDS (8 points/thread) ----
    for (int i = tid; i < QWIN; i += 256) {
        const int t = i >> 5, c = i & 31;
        const float* Q = Bcl + ((size_t)b * NPTS + qs * QWIN + i) * 3;
        const float qx = Q[0], qy = Q[1], qz = Q[2];

        const _Float16 hx = (_Float16)qx, hy = (_Float16)qy, hz = (_Float16)qz;
        const _Float16 lx = (_Float16)(qx - (float)hx);
        const _Float16 ly = (_Float16)(qy - (float)hy);
        const _Float16 lz = (_Float16)(qz - (float)hz);
        const float sq = fmaf(qx, qx, fmaf(qy, qy, qz * qz));
        const _Float16 sh = (_Float16)sq;
        const _Float16 sl = (_Float16)(sq - (float)sh);

        const _Float16 nhx = (_Float16)(-2.0f * (float)hx);
        const _Float16 nhy = (_Float16)(-2.0f * (float)hy);
        const _Float16 nhz = (_Float16)(-2.0f * (float)hz);
        const _Float16 nlx = (_Float16)(-2.0f * (float)lx);
        const _Float16 nly = (_Float16)(-2.0f * (float)ly);
        const _Float16 nlz = (_Float16)(-2.0f * (float)lz);

        Bf[t * 64 + c]      = (half8){nhx, nhy, nhz, nlx, nly, nlz, nhx, nhy};
        Bf[t * 64 + 32 + c] = (half8){nhz, one, one, sh,  sl,  zz,  zz,  zz};
    }

    // ---- A fragments (rows pbase+col, pbase+32+col) ----
    half8 a0, a1;
    #pragma unroll
    for (int h = 0; h < 2; ++h) {
        const float* P = Acl + ((size_t)b * NPTS + pbase + h * 32 + col) * 3;
        const float px = P[0], py = P[1], pz = P[2];
        const _Float16 hx = (_Float16)px, hy = (_Float16)py, hz = (_Float16)pz;
        const _Float16 lx = (_Float16)(px - (float)hx);
        const _Float16 ly = (_Float16)(py - (float)hy);
        const _Float16 lz = (_Float16)(pz - (float)hz);
        const float sq1 = fmaf(px, px, fmaf(py, py, pz * pz));
        const _Float16 sh = (_Float16)sq1;
        const _Float16 sl = (_Float16)(sq1 - (float)sh);
        half8 a;
        if (g == 0) a = (half8){hx, hy, hz, hx, hy, hz, lx, ly};
        else        a = (half8){lz, sh, sl, one, one, zz, zz, zz};
        if (h == 0) a0 = a; else a1 = a;
    }

    f32x16 rowmin0, rowmin1;
    #pragma unroll
    for (int r = 0; r < 16; ++r) { rowmin0[r] = 3.402823466e+38f;
                                   rowmin1[r] = 3.402823466e+38f; }
    f32x16 zero16;
    #pragma unroll
    for (int r = 0; r < 16; ++r) zero16[r] = 0.0f;

    __syncthreads();   // LDS build complete; read-only from here on

    // ---- 4-tile register ring; LDS is read-only -> no barriers in loop ----
    half8 p0 = Bf[0 * 64 + lane], p1 = Bf[1 * 64 + lane];
    half8 p2 = Bf[2 * 64 + lane], p3 = Bf[3 * 64 + lane];

    #pragma unroll 4
    for (int t = 0; t < TPW; t += 2) {
        // prefetch tiles t+4, t+5 (tail reads land in the 4 pad tiles,
        // loaded but never consumed)
        const half8 m0 = Bf[(t + 4) * 64 + lane];
        const half8 m1 = Bf[(t + 5) * 64 + lane];

        f32x16 acc00, acc01, acc10, acc11;
        MFMA_V(acc00, a0, p0, zero16);
        MFMA_V(acc01, a0, p1, zero16);
        MFMA_V(acc10, a1, p0, zero16);
        MFMA_V(acc11, a1, p1, zero16);

        // hazard gap: no VALU read of accs until >=16 cyc after last issue;
        // walls also stop ds_reads drifting across iterations (pressure bound)
        __builtin_amdgcn_sched_barrier(0);
        asm volatile("s_nop 7\n\ts_nop 7");
        __builtin_amdgcn_sched_barrier(0);

        #pragma unroll
        for (int r = 0; r < 16; ++r)
            rowmin0[r] = fminf(fminf(acc00[r], acc01[r]), rowmin0[r]);
        #pragma unroll
        for (int r = 0; r < 16; ++r)
            rowmin1[r] = fminf(fminf(acc10[r], acc11[r]), rowmin1[r]);

        p0 = p2; p1 = p3; p2 = m0; p3 = m1;
    }

    // ---- cross-column min (32 cols) + store; row map (r&3)+8*(r>>2)+4*g ----
    const size_t obase = (((size_t)dir * NB + b) * SPLITS + qs) * NPTS + pbase;
    #pragma unroll
    for (int r = 0; r < 16; ++r) {
        float v = rowmin0[r];
        v = fminf(v, __shfl_xor(v, 1, 64));
        v = fminf(v, __shfl_xor(v, 2, 64));
        v = fminf(v, __shfl_xor(v, 4, 64));
        v = fminf(v, __shfl_xor(v, 8, 64));
        v = fminf(v, __shfl_xor(v, 16, 64));
        float u = rowmin1[r];
        u = fminf(u, __shfl_xor(u, 1, 64));
        u = fminf(u, __shfl_xor(u, 2, 64));
        u = fminf(u, __shfl_xor(u, 4, 64));
        u = fminf(u, __shfl_xor(u, 8, 64));
        u = fminf(u, __shfl_xor(u, 16, 64));
        if (col == 0) {
            const int row = (r & 3) + 8 * (r >> 2) + 4 * g;
            ws_row[obase + row]      = v;
            ws_row[obase + 32 + row] = u;
        }
    }
}

// ---------- reduce: 256 blocks; min over 4 splits, block partial sums ----------
__global__ __launch_bounds__(256) void chamfer_reduce(
    const float* __restrict__ ws_row, float* __restrict__ partial)
{
    int bid = blockIdx.x;                    // 2 dir x 4 b x 32 slices
    const int sl  = bid & 31; bid >>= 5;
    const int b   = bid & 3;  bid >>= 2;
    const int dir = bid;

    const int p = sl * 256 + threadIdx.x;
    const float* base = ws_row + (((size_t)dir * NB + b) * SPLITS) * NPTS + p;
    float sum = fminf(fminf(base[0],        base[NPTS]),
                      fminf(base[2 * NPTS], base[3 * NPTS]));

    for (int off = 32; off; off >>= 1) sum += __shfl_down(sum, off, 64);
    __shared__ float red[4];
    if (!(threadIdx.x & 63)) red[threadIdx.x >> 6] = sum;
    __syncthreads();
    if (!threadIdx.x)
        partial[blockIdx.x] = red[0] + red[1] + red[2] + red[3];
}

// ---------- final: 4 blocks x 64 thr; each b sums its 64 partials ----------
__global__ __launch_bounds__(64) void chamfer_final(
    const float* __restrict__ partial, float* __restrict__ out)
{
    const int b = blockIdx.x, t = threadIdx.x;
    const int dir = t >> 5, sl = t & 31;
    float v = partial[(((size_t)dir * NB + b) << 5) + sl];
    for (int off = 32; off; off >>= 1) v += __shfl_down(v, off, 64);
    if (!t) out[b] = v * (1.0f / (float)NPTS);
}

extern "C" void kernel_launch(void* const* d_in, const int* in_sizes, int n_in,
                              void* d_out, int out_size, void* d_ws, size_t ws_size,
                              hipStream_t stream)
{
    const float* pc1 = (const float*)d_in[0];
    const float* pc2 = (const float*)d_in[1];
    float* out = (float*)d_out;

    char* ws = (char*)d_ws;
    float* ws_row  = (float*)ws;                // 2*4*4*8192*4B = 1 MiB
    float* partial = (float*)(ws + (1 << 20));  // 1 KiB

    chamfer_main<<<1024, 256, 0, stream>>>(pc1, pc2, ws_row);
    chamfer_reduce<<<256, 256, 0, stream>>>(ws_row, partial);
    chamfer_final<<<NB, 64, 0, stream>>>(partial, out);
}